// Round 2
// baseline (2430.112 us; speedup 1.0000x reference)
//
#include <hip/hip_runtime.h>
#include <cstdint>
#include <cstddef>

#define NN 50000
#define NE 800000
#define HD 64

// ---------------- elementwise log1p ----------------
__global__ void k_log1p(const float* __restrict__ in, float* __restrict__ out, int n) {
    int i = blockIdx.x * blockDim.x + threadIdx.x;
    if (i < n) out[i] = __logf(in[i] + 1.0f);
}

// ---------------- CSR build: histogram ----------------
__global__ void k_hist(const int* __restrict__ ei, int* __restrict__ cnt) {
    int e = blockIdx.x * blockDim.x + threadIdx.x;
    if (e < NE) {
        int d = ei[NE + e];
        atomicAdd(&cnt[d], 1);
    }
}

// ---------------- CSR build: single-block exclusive scan ----------------
__global__ __launch_bounds__(1024) void k_scan(const int* __restrict__ cnt,
                                               int* __restrict__ row_start,
                                               int* __restrict__ cur) {
    __shared__ int ssum[1024];
    const int T = 1024, C = (NN + T - 1) / T;
    int t = threadIdx.x;
    int beg = t * C, end = min(beg + C, NN);
    int s = 0;
    for (int i = beg; i < end; ++i) s += cnt[i];
    ssum[t] = s;
    __syncthreads();
    for (int off = 1; off < T; off <<= 1) {
        int v = (t >= off) ? ssum[t - off] : 0;
        __syncthreads();
        ssum[t] += v;
        __syncthreads();
    }
    int pre = (t == 0) ? 0 : ssum[t - 1];
    for (int i = beg; i < end; ++i) {
        row_start[i] = pre;
        pre += cnt[i];
        cur[i] = 0;
    }
    if (t == T - 1) row_start[NN] = ssum[T - 1];
}

// ---------------- CSR build: scatter edge ids sorted by dst ----------------
__global__ void k_scatter(const int* __restrict__ ei, const int* __restrict__ row_start,
                          int* __restrict__ cur, int* __restrict__ perm) {
    int e = blockIdx.x * blockDim.x + threadIdx.x;
    if (e < NE) {
        int d = ei[NE + e];
        int pos = row_start[d] + atomicAdd(&cur[d], 1);
        perm[pos] = e;
    }
}

// ---------------- fused 2-matrix GEMM: O0 = h@W0+B0, O1 = h@W1+B1 ----------------
// block = 256 (4 waves); each block: 32 nodes; each wave: 8 nodes; lane = out col.
// LDS: weights (2*DIN*64) + biases + x tile (32*DIN). DIN=64 -> 40.5 KB -> 3 blocks/CU.
template <int DIN>
__global__ __launch_bounds__(256) void k_pair_gemm(
    const float* __restrict__ h,
    const float* __restrict__ W0, const float* __restrict__ B0,
    const float* __restrict__ W1, const float* __restrict__ B1,
    float* __restrict__ O0, float* __restrict__ O1) {
    __shared__ float wl[2 * DIN * 64];
    __shared__ float bl[128];
    __shared__ float xt[32 * DIN];
    const int tid = threadIdx.x;
    for (int i = tid; i < DIN * 64; i += 256) {
        wl[i] = W0[i];
        wl[DIN * 64 + i] = W1[i];
    }
    if (tid < 64) {
        bl[tid] = B0[tid];
        bl[64 + tid] = B1[tid];
    }
    const int base = blockIdx.x * 32;
    const int cnt = min(32, NN - base);
    for (int i = tid; i < cnt * DIN; i += 256) xt[i] = h[(size_t)base * DIN + i];
    __syncthreads();

    const int lane = tid & 63, wvi = tid >> 6;
    float a0[8], a1[8];
#pragma unroll
    for (int n = 0; n < 8; n++) {
        a0[n] = bl[lane];
        a1[n] = bl[64 + lane];
    }
    if constexpr (DIN % 4 == 0) {
        const float4* xt4 = (const float4*)xt;
        for (int jq = 0; jq < DIN / 4; ++jq) {
            float4 xv[8];
#pragma unroll
            for (int n = 0; n < 8; n++) xv[n] = xt4[(wvi * 8 + n) * (DIN / 4) + jq];
#pragma unroll
            for (int jj = 0; jj < 4; jj++) {
                float w0 = wl[(jq * 4 + jj) * 64 + lane];
                float w1 = wl[DIN * 64 + (jq * 4 + jj) * 64 + lane];
#pragma unroll
                for (int n = 0; n < 8; n++) {
                    float xb = (jj == 0) ? xv[n].x : (jj == 1) ? xv[n].y : (jj == 2) ? xv[n].z : xv[n].w;
                    a0[n] = fmaf(xb, w0, a0[n]);
                    a1[n] = fmaf(xb, w1, a1[n]);
                }
            }
        }
    } else {
        for (int j = 0; j < DIN; ++j) {
            float w0 = wl[j * 64 + lane];
            float w1 = wl[DIN * 64 + j * 64 + lane];
#pragma unroll
            for (int n = 0; n < 8; n++) {
                float xb = xt[(wvi * 8 + n) * DIN + j];
                a0[n] = fmaf(xb, w0, a0[n]);
                a1[n] = fmaf(xb, w1, a1[n]);
            }
        }
    }
#pragma unroll
    for (int n = 0; n < 8; n++) {
        int node = base + wvi * 8 + n;
        if (node < NN) {
            O0[(size_t)node * 64 + lane] = a0[n];
            O1[(size_t)node * 64 + lane] = a1[n];
        }
    }
}

// ---------------- per-dst-node online-softmax aggregation ----------------
// one wave per dst node; lane j owns HID element j. CSR edge list by dst.
// ee = e5[eid] @ wE computed on the fly (5 FMA). hout = agg + skip.
__global__ __launch_bounds__(256) void k_agg(
    const float* __restrict__ q, const float* __restrict__ kk, const float* __restrict__ vv,
    const float* __restrict__ sk, const float* __restrict__ e5, const float* __restrict__ wE,
    const int* __restrict__ ei, const int* __restrict__ row_start,
    const int* __restrict__ perm, float* __restrict__ hout) {
    const int lane = threadIdx.x & 63;
    int node = __builtin_amdgcn_readfirstlane(blockIdx.x * 4 + (threadIdx.x >> 6));
    if (node >= NN) return;
    const float wec0 = wE[lane], wec1 = wE[64 + lane], wec2 = wE[128 + lane],
                wec3 = wE[192 + lane], wec4 = wE[256 + lane];
    const float qj = q[(size_t)node * 64 + lane];
    float m = -1e30f, l = 0.f, acc = 0.f;
    const int beg = row_start[node], end = row_start[node + 1];
    for (int p = beg; p < end; ++p) {
        const int eid = perm[p];                 // uniform -> s_load
        const int src = ei[eid];                 // uniform -> s_load
        const float* er = e5 + (size_t)eid * 5;  // uniform row
        float ee = er[0] * wec0;
        ee = fmaf(er[1], wec1, ee);
        ee = fmaf(er[2], wec2, ee);
        ee = fmaf(er[3], wec3, ee);
        ee = fmaf(er[4], wec4, ee);
        float kj = kk[(size_t)src * 64 + lane] + ee;
        float vj = vv[(size_t)src * 64 + lane] + ee;
        float t = qj * kj;
#pragma unroll
        for (int off = 32; off > 0; off >>= 1) t += __shfl_xor(t, off, 64);
        float logit = t * 0.125f;
        float nm = fmaxf(m, logit);
        float scl = __expf(m - nm);
        float pw = __expf(logit - nm);
        l = l * scl + pw;
        acc = acc * scl + pw * vj;
        m = nm;
    }
    float o = sk[(size_t)node * 64 + lane];
    if (end > beg) o += acc / l;
    hout[(size_t)node * 64 + lane] = o;
}

// ---------------- final linear HID -> 1 ----------------
__global__ __launch_bounds__(256) void k_final(const float* __restrict__ h,
                                               const float* __restrict__ lw,
                                               const float* __restrict__ lb,
                                               float* __restrict__ out) {
    const int lane = threadIdx.x & 63;
    int node = blockIdx.x * 4 + (threadIdx.x >> 6);
    if (node >= NN) return;
    float t = h[(size_t)node * 64 + lane] * lw[lane];
#pragma unroll
    for (int off = 32; off > 0; off >>= 1) t += __shfl_xor(t, off, 64);
    if (lane == 0) out[node] = t + lb[0];
}

extern "C" void kernel_launch(void* const* d_in, const int* in_sizes, int n_in,
                              void* d_out, int out_size, void* d_ws, size_t ws_size,
                              hipStream_t stream) {
    const float* x = (const float*)d_in[0];
    const int* ei = (const int*)d_in[1];  // int32 per harness contract
    const float* ea = (const float*)d_in[2];
    const float* w1q = (const float*)d_in[3];
    const float* b1q = (const float*)d_in[4];
    const float* w1k = (const float*)d_in[5];
    const float* b1k = (const float*)d_in[6];
    const float* w1v = (const float*)d_in[7];
    const float* b1v = (const float*)d_in[8];
    const float* w1e = (const float*)d_in[9];
    const float* w1s = (const float*)d_in[10];
    const float* b1s = (const float*)d_in[11];
    const float* wq = (const float*)d_in[12];
    const float* bq = (const float*)d_in[13];
    const float* wk = (const float*)d_in[14];
    const float* bk = (const float*)d_in[15];
    const float* wv = (const float*)d_in[16];
    const float* bv = (const float*)d_in[17];
    const float* we = (const float*)d_in[18];
    const float* ws = (const float*)d_in[19];
    const float* bs = (const float*)d_in[20];
    const float* lw = (const float*)d_in[21];
    const float* lb = (const float*)d_in[22];

    // ---- workspace carve (all 256B aligned), ~86 MB total ----
    uintptr_t p = (uintptr_t)d_ws;
    auto alloc = [&](size_t bytes) -> void* {
        void* r = (void*)p;
        p += (bytes + 255) & ~(size_t)255;
        return r;
    };
    float* e5 = (float*)alloc((size_t)NE * 5 * 4);        // 16 MB
    float* h0 = (float*)alloc((size_t)NN * 10 * 4);       // 2 MB
    float* hb = (float*)alloc((size_t)NN * HD * 4);       // B0: h (agg output)
    float* kb = (float*)alloc((size_t)NN * HD * 4);       // B1: k
    float* vb = (float*)alloc((size_t)NN * HD * 4);       // B2: v
    float* sb = (float*)alloc((size_t)NN * HD * 4);       // B3: s
    float* qb = (float*)alloc((size_t)NN * HD * 4);       // B4: q
    int* row_start = (int*)alloc((size_t)(NN + 1) * 4);
    int* cnt = (int*)alloc((size_t)NN * 4);
    int* cur = (int*)alloc((size_t)NN * 4);
    int* perm = (int*)alloc((size_t)NE * 4);

    // ---- preprocess (once per call) ----
    hipMemsetAsync(cnt, 0, (size_t)NN * 4, stream);
    k_log1p<<<(NE * 5 + 255) / 256, 256, 0, stream>>>(ea, e5, NE * 5);
    k_log1p<<<(NN * 10 + 255) / 256, 256, 0, stream>>>(x, h0, NN * 10);
    k_hist<<<(NE + 255) / 256, 256, 0, stream>>>(ei, cnt);
    k_scan<<<1, 1024, 0, stream>>>(cnt, row_start, cur);
    k_scatter<<<(NE + 255) / 256, 256, 0, stream>>>(ei, row_start, cur, perm);

    const int gemm_grid = (NN + 31) / 32;  // 1563
    const int agg_grid = (NN + 3) / 4;     // 12500

    // ---- layer 1 (DIN=10) ----
    k_pair_gemm<10><<<gemm_grid, 256, 0, stream>>>(h0, w1q, b1q, w1k, b1k, qb, kb);
    k_pair_gemm<10><<<gemm_grid, 256, 0, stream>>>(h0, w1v, b1v, w1s, b1s, vb, sb);
    k_agg<<<agg_grid, 256, 0, stream>>>(qb, kb, vb, sb, e5, w1e, ei, row_start, perm, hb);

    // ---- layers 2..6 (DIN=64): read hb, write q/k/v/s, agg back into hb ----
    for (int i = 0; i < 5; ++i) {
        k_pair_gemm<64><<<gemm_grid, 256, 0, stream>>>(hb, wq + i * 4096, bq + i * 64,
                                                       wk + i * 4096, bk + i * 64, qb, kb);
        k_pair_gemm<64><<<gemm_grid, 256, 0, stream>>>(hb, wv + i * 4096, bv + i * 64,
                                                       ws + i * 4096, bs + i * 64, vb, sb);
        k_agg<<<agg_grid, 256, 0, stream>>>(qb, kb, vb, sb, e5, we + i * 320, ei, row_start,
                                            perm, hb);
    }

    // ---- final linear ----
    k_final<<<agg_grid, 256, 0, stream>>>(hb, lw, lb, (float*)d_out);
}

// Round 3
// 944.426 us; speedup vs baseline: 2.5731x; 2.5731x over previous
//
#include <hip/hip_runtime.h>
#include <cstdint>
#include <cstddef>

#define NN 50000
#define NE 800000
#define HD 64

// ---------------- elementwise log1p (node features) ----------------
__global__ void k_log1p(const float* __restrict__ in, float* __restrict__ out, int n) {
    int i = blockIdx.x * blockDim.x + threadIdx.x;
    if (i < n) out[i] = __logf(in[i] + 1.0f);
}

// ---------------- CSR build: histogram ----------------
__global__ void k_hist(const int* __restrict__ ei, int* __restrict__ cnt) {
    int e = blockIdx.x * blockDim.x + threadIdx.x;
    if (e < NE) atomicAdd(&cnt[ei[NE + e]], 1);
}

// ---------------- CSR build: single-block exclusive scan ----------------
__global__ __launch_bounds__(1024) void k_scan(const int* __restrict__ cnt,
                                               int* __restrict__ row_start,
                                               int* __restrict__ cur) {
    __shared__ int ssum[1024];
    const int T = 1024, C = (NN + T - 1) / T;
    int t = threadIdx.x;
    int beg = t * C, end = min(beg + C, NN);
    int s = 0;
    for (int i = beg; i < end; ++i) s += cnt[i];
    ssum[t] = s;
    __syncthreads();
    for (int off = 1; off < T; off <<= 1) {
        int v = (t >= off) ? ssum[t - off] : 0;
        __syncthreads();
        ssum[t] += v;
        __syncthreads();
    }
    int pre = (t == 0) ? 0 : ssum[t - 1];
    for (int i = beg; i < end; ++i) {
        row_start[i] = pre;
        pre += cnt[i];
        cur[i] = 0;
    }
    if (t == T - 1) row_start[NN] = ssum[T - 1];
}

// ------- CSR build: scatter src + log1p(edge_attr) into dst-sorted order -------
// e5s rows padded to 8 floats (32 B, 16B-aligned) for float4 loads in k_agg.
__global__ void k_scatter(const int* __restrict__ ei, const float* __restrict__ ea,
                          const int* __restrict__ row_start, int* __restrict__ cur,
                          int* __restrict__ srcs, float* __restrict__ e5s) {
    int e = blockIdx.x * blockDim.x + threadIdx.x;
    if (e < NE) {
        int d = ei[NE + e];
        int pos = row_start[d] + atomicAdd(&cur[d], 1);
        srcs[pos] = ei[e];
        float4 v4;
        v4.x = __logf(ea[e * 5 + 0] + 1.f);
        v4.y = __logf(ea[e * 5 + 1] + 1.f);
        v4.z = __logf(ea[e * 5 + 2] + 1.f);
        v4.w = __logf(ea[e * 5 + 3] + 1.f);
        *(float4*)(e5s + (size_t)pos * 8) = v4;
        e5s[(size_t)pos * 8 + 4] = __logf(ea[e * 5 + 4] + 1.f);
    }
}

// ---------------- pair GEMM: O0 = h@W0+B0, O1 = h@W1+B1 ----------------
// Wave-parallel: lane = out col; weights VGPR-resident (2*DIN regs);
// x rows via wave-uniform scalar loads (readfirstlane-forced base -> s_load).
// No LDS, no spill. NB nodes per iteration (ILP via 2*NB FMA chains).
template <int DIN, int NB>
__global__ __launch_bounds__(256) void k_pg(
    const float* __restrict__ h,
    const float* __restrict__ W0, const float* __restrict__ B0,
    const float* __restrict__ W1, const float* __restrict__ B1,
    float* __restrict__ O0, int ldo0, float* __restrict__ O1, int ldo1) {
    const int lane = threadIdx.x & 63;
    const int wid = (blockIdx.x * blockDim.x + threadIdx.x) >> 6;
    const int nw = (gridDim.x * blockDim.x) >> 6;
    float w0[DIN], w1[DIN];
#pragma unroll
    for (int j = 0; j < DIN; ++j) {
        w0[j] = W0[j * 64 + lane];
        w1[j] = W1[j * 64 + lane];
    }
    const float b0 = B0[lane], b1 = B1[lane];
    const int nbatch = NN / NB;  // 50000 divisible by NB in {1,4}
    for (int b = wid; b < nbatch; b += nw) {
        const int n0 = __builtin_amdgcn_readfirstlane(b * NB);
        const float* hp = h + (size_t)n0 * DIN;
        float a0[NB], a1[NB];
#pragma unroll
        for (int n = 0; n < NB; ++n) {
            a0[n] = b0;
            a1[n] = b1;
        }
#pragma unroll
        for (int n = 0; n < NB; ++n) {
#pragma unroll
            for (int j = 0; j < DIN; ++j) {
                const float xv = hp[n * DIN + j];  // scalar (uniform) load
                a0[n] = fmaf(xv, w0[j], a0[n]);
                a1[n] = fmaf(xv, w1[j], a1[n]);
            }
        }
#pragma unroll
        for (int n = 0; n < NB; ++n) {
            O0[(size_t)(n0 + n) * ldo0 + lane] = a0[n];
            O1[(size_t)(n0 + n) * ldo1 + lane] = a1[n];
        }
    }
}

// ---------------- per-dst-node online-softmax aggregation, 4 edges/iter ----------------
// One wave per dst node. Lanes: g = lane>>4 (edge slot), t = lane&15 (feature quarter).
// Each lane owns HID elements [t*4, t*4+4). kv interleaved: k at src*128, v at src*128+64.
__global__ __launch_bounds__(256) void k_agg(
    const float* __restrict__ q, const float* __restrict__ kv,
    const float* __restrict__ sk, const float* __restrict__ e5s,
    const int* __restrict__ srcs, const float* __restrict__ wE,
    const int* __restrict__ row_start, float* __restrict__ hout) {
    const int lane = threadIdx.x & 63;
    const int g = lane >> 4, t = lane & 15;
    const int node = __builtin_amdgcn_readfirstlane(blockIdx.x * 4 + (threadIdx.x >> 6));
    if (node >= NN) return;
    float4 we4[5];
#pragma unroll
    for (int c = 0; c < 5; ++c) we4[c] = *(const float4*)(wE + c * 64 + t * 4);
    const float4 q4 = *(const float4*)(q + (size_t)node * 64 + t * 4);
    const int beg = row_start[node], end = row_start[node + 1];
    float m = -1e30f, l = 0.f;
    float4 acc = {0.f, 0.f, 0.f, 0.f};
    for (int p = beg; p < end; p += 4) {
        const int myp = p + g;
        const bool act = myp < end;
        const int pp = act ? myp : beg;
        const int src = srcs[pp];
        const float4 e04 = *(const float4*)(e5s + (size_t)pp * 8);
        const float e4v = e5s[(size_t)pp * 8 + 4];
        const float* kvp = kv + (size_t)src * 128 + t * 4;
        float4 k4 = *(const float4*)(kvp);
        float4 v4 = *(const float4*)(kvp + 64);
        float4 ee;
        ee.x = e04.x * we4[0].x;
        ee.y = e04.x * we4[0].y;
        ee.z = e04.x * we4[0].z;
        ee.w = e04.x * we4[0].w;
        ee.x = fmaf(e04.y, we4[1].x, ee.x);
        ee.y = fmaf(e04.y, we4[1].y, ee.y);
        ee.z = fmaf(e04.y, we4[1].z, ee.z);
        ee.w = fmaf(e04.y, we4[1].w, ee.w);
        ee.x = fmaf(e04.z, we4[2].x, ee.x);
        ee.y = fmaf(e04.z, we4[2].y, ee.y);
        ee.z = fmaf(e04.z, we4[2].z, ee.z);
        ee.w = fmaf(e04.z, we4[2].w, ee.w);
        ee.x = fmaf(e04.w, we4[3].x, ee.x);
        ee.y = fmaf(e04.w, we4[3].y, ee.y);
        ee.z = fmaf(e04.w, we4[3].z, ee.z);
        ee.w = fmaf(e04.w, we4[3].w, ee.w);
        ee.x = fmaf(e4v, we4[4].x, ee.x);
        ee.y = fmaf(e4v, we4[4].y, ee.y);
        ee.z = fmaf(e4v, we4[4].z, ee.z);
        ee.w = fmaf(e4v, we4[4].w, ee.w);
        k4.x += ee.x; k4.y += ee.y; k4.z += ee.z; k4.w += ee.w;
        v4.x += ee.x; v4.y += ee.y; v4.z += ee.z; v4.w += ee.w;
        float d = q4.x * k4.x;
        d = fmaf(q4.y, k4.y, d);
        d = fmaf(q4.z, k4.z, d);
        d = fmaf(q4.w, k4.w, d);
        d += __shfl_xor(d, 1);
        d += __shfl_xor(d, 2);
        d += __shfl_xor(d, 4);
        d += __shfl_xor(d, 8);
        const float la = act ? d * 0.125f : -1e30f;
        const float lb = __shfl_xor(la, 16);
        const float lc = __shfl_xor(la, 32);
        const float ld = __shfl_xor(lb, 32);
        const float nm = fmaxf(fmaxf(fmaxf(la, lb), fmaxf(lc, ld)), m);
        const float scl = __expf(m - nm);
        const float pa = __expf(la - nm);
        const float pb = __expf(lb - nm);
        const float pc = __expf(lc - nm);
        const float pd = __expf(ld - nm);
        l = fmaf(l, scl, (pa + pb) + (pc + pd));
        acc.x = fmaf(acc.x, scl, pa * v4.x);
        acc.y = fmaf(acc.y, scl, pa * v4.y);
        acc.z = fmaf(acc.z, scl, pa * v4.z);
        acc.w = fmaf(acc.w, scl, pa * v4.w);
        m = nm;
    }
    // sum partial accumulators across the 4 groups
    acc.x += __shfl_xor(acc.x, 16);
    acc.y += __shfl_xor(acc.y, 16);
    acc.z += __shfl_xor(acc.z, 16);
    acc.w += __shfl_xor(acc.w, 16);
    acc.x += __shfl_xor(acc.x, 32);
    acc.y += __shfl_xor(acc.y, 32);
    acc.z += __shfl_xor(acc.z, 32);
    acc.w += __shfl_xor(acc.w, 32);
    float4 o = *(const float4*)(sk + (size_t)node * 64 + t * 4);
    if (end > beg) {
        const float rl = 1.f / l;
        o.x = fmaf(acc.x, rl, o.x);
        o.y = fmaf(acc.y, rl, o.y);
        o.z = fmaf(acc.z, rl, o.z);
        o.w = fmaf(acc.w, rl, o.w);
    }
    if (g == 0) *(float4*)(hout + (size_t)node * 64 + t * 4) = o;
}

// ---------------- final linear HID -> 1 ----------------
__global__ __launch_bounds__(256) void k_final(const float* __restrict__ h,
                                               const float* __restrict__ lw,
                                               const float* __restrict__ lb,
                                               float* __restrict__ out) {
    const int lane = threadIdx.x & 63;
    int node = blockIdx.x * 4 + (threadIdx.x >> 6);
    if (node >= NN) return;
    float t = h[(size_t)node * 64 + lane] * lw[lane];
#pragma unroll
    for (int off = 32; off > 0; off >>= 1) t += __shfl_xor(t, off, 64);
    if (lane == 0) out[node] = t + lb[0];
}

extern "C" void kernel_launch(void* const* d_in, const int* in_sizes, int n_in,
                              void* d_out, int out_size, void* d_ws, size_t ws_size,
                              hipStream_t stream) {
    const float* x = (const float*)d_in[0];
    const int* ei = (const int*)d_in[1];  // int32 per harness contract
    const float* ea = (const float*)d_in[2];
    const float* w1q = (const float*)d_in[3];
    const float* b1q = (const float*)d_in[4];
    const float* w1k = (const float*)d_in[5];
    const float* b1k = (const float*)d_in[6];
    const float* w1v = (const float*)d_in[7];
    const float* b1v = (const float*)d_in[8];
    const float* w1e = (const float*)d_in[9];
    const float* w1s = (const float*)d_in[10];
    const float* b1s = (const float*)d_in[11];
    const float* wq = (const float*)d_in[12];
    const float* bq = (const float*)d_in[13];
    const float* wk = (const float*)d_in[14];
    const float* bk = (const float*)d_in[15];
    const float* wv = (const float*)d_in[16];
    const float* bv = (const float*)d_in[17];
    const float* we = (const float*)d_in[18];
    const float* ws = (const float*)d_in[19];
    const float* bs = (const float*)d_in[20];
    const float* lw = (const float*)d_in[21];
    const float* lb = (const float*)d_in[22];

    // ---- workspace carve (256B aligned), ~95 MB ----
    uintptr_t p = (uintptr_t)d_ws;
    auto alloc = [&](size_t bytes) -> void* {
        void* r = (void*)p;
        p += (bytes + 255) & ~(size_t)255;
        return r;
    };
    float* e5s = (float*)alloc((size_t)NE * 8 * 4);   // 25.6 MB, dst-sorted padded rows
    float* h0 = (float*)alloc((size_t)NN * 10 * 4);   // 2 MB
    float* hb = (float*)alloc((size_t)NN * HD * 4);   // 12.8 MB
    float* kvb = (float*)alloc((size_t)NN * 128 * 4); // 25.6 MB interleaved k|v
    float* qb = (float*)alloc((size_t)NN * HD * 4);
    float* sb = (float*)alloc((size_t)NN * HD * 4);
    int* srcs = (int*)alloc((size_t)NE * 4);          // 3.2 MB dst-sorted src ids
    int* row_start = (int*)alloc((size_t)(NN + 1) * 4);
    int* cnt = (int*)alloc((size_t)NN * 4);
    int* cur = (int*)alloc((size_t)NN * 4);

    // ---- preprocess (once per call) ----
    hipMemsetAsync(cnt, 0, (size_t)NN * 4, stream);
    k_log1p<<<(NN * 10 + 255) / 256, 256, 0, stream>>>(x, h0, NN * 10);
    k_hist<<<(NE + 255) / 256, 256, 0, stream>>>(ei, cnt);
    k_scan<<<1, 1024, 0, stream>>>(cnt, row_start, cur);
    k_scatter<<<(NE + 255) / 256, 256, 0, stream>>>(ei, ea, row_start, cur, srcs, e5s);

    const int gg = 512;                 // gemm grid (2048 waves)
    const int agg_grid = (NN + 3) / 4;  // 12500

    // ---- layer 1 (DIN=10, 4 nodes/iter) ----
    k_pg<10, 4><<<gg, 256, 0, stream>>>(h0, w1k, b1k, w1v, b1v, kvb, 128, kvb + 64, 128);
    k_pg<10, 4><<<gg, 256, 0, stream>>>(h0, w1q, b1q, w1s, b1s, qb, 64, sb, 64);
    k_agg<<<agg_grid, 256, 0, stream>>>(qb, kvb, sb, e5s, srcs, w1e, row_start, hb);

    // ---- layers 2..6 (DIN=64) ----
    for (int i = 0; i < 5; ++i) {
        k_pg<64, 1><<<gg, 256, 0, stream>>>(hb, wk + i * 4096, bk + i * 64,
                                            wv + i * 4096, bv + i * 64, kvb, 128, kvb + 64, 128);
        k_pg<64, 1><<<gg, 256, 0, stream>>>(hb, wq + i * 4096, bq + i * 64,
                                            ws + i * 4096, bs + i * 64, qb, 64, sb, 64);
        k_agg<<<agg_grid, 256, 0, stream>>>(qb, kvb, sb, e5s, srcs, we + i * 320, row_start, hb);
    }

    // ---- final linear ----
    k_final<<<agg_grid, 256, 0, stream>>>(hb, lw, lb, (float*)d_out);
}

// Round 4
// 878.809 us; speedup vs baseline: 2.7652x; 1.0747x over previous
//
#include <hip/hip_runtime.h>
#include <cstdint>
#include <cstddef>

#define NN 50000
#define NE 800000
#define HD 64
#define SB 49  // scan blocks = ceil(50000/1024)

// ---------------- elementwise log1p (node features) ----------------
__global__ void k_log1p(const float* __restrict__ in, float* __restrict__ out, int n) {
    int i = blockIdx.x * blockDim.x + threadIdx.x;
    if (i < n) out[i] = __logf(in[i] + 1.0f);
}

// ---------------- CSR build: histogram ----------------
__global__ void k_hist(const int* __restrict__ ei, int* __restrict__ cnt) {
    int e = blockIdx.x * blockDim.x + threadIdx.x;
    if (e < NE) atomicAdd(&cnt[ei[NE + e]], 1);
}

// ------- hierarchical scan, phase 1: per-block local exclusive scan -------
// 49 blocks x 256 thr, 4 elems/thread (1024/block).
__global__ __launch_bounds__(256) void k_scan1(const int* __restrict__ cnt,
                                               int* __restrict__ row_start,
                                               int* __restrict__ bsum) {
    __shared__ int ssum[256];
    const int tid = threadIdx.x, b = blockIdx.x;
    const int i0 = b * 1024 + tid * 4;
    int c0 = 0, c1 = 0, c2 = 0, c3 = 0;
    if (i0 + 3 < NN) {
        const int4 c = *(const int4*)(cnt + i0);
        c0 = c.x; c1 = c.y; c2 = c.z; c3 = c.w;
    } else {
        if (i0 + 0 < NN) c0 = cnt[i0 + 0];
        if (i0 + 1 < NN) c1 = cnt[i0 + 1];
        if (i0 + 2 < NN) c2 = cnt[i0 + 2];
        if (i0 + 3 < NN) c3 = cnt[i0 + 3];
    }
    ssum[tid] = c0 + c1 + c2 + c3;
    __syncthreads();
    for (int off = 1; off < 256; off <<= 1) {
        int v = (tid >= off) ? ssum[tid - off] : 0;
        __syncthreads();
        ssum[tid] += v;
        __syncthreads();
    }
    int ex = (tid == 0) ? 0 : ssum[tid - 1];
    if (i0 + 0 < NN) row_start[i0 + 0] = ex;
    ex += c0;
    if (i0 + 1 < NN) row_start[i0 + 1] = ex;
    ex += c1;
    if (i0 + 2 < NN) row_start[i0 + 2] = ex;
    ex += c2;
    if (i0 + 3 < NN) row_start[i0 + 3] = ex;
    if (tid == 255) bsum[b] = ssum[255];
}

// ------- scan phase 2: scan the 49 block sums (1 block, 64 thr) -------
__global__ __launch_bounds__(64) void k_scan2(const int* __restrict__ bsum,
                                              int* __restrict__ boff,
                                              int* __restrict__ row_start) {
    __shared__ int s[64];
    const int t = threadIdx.x;
    s[t] = (t < SB) ? bsum[t] : 0;
    __syncthreads();
    for (int off = 1; off < 64; off <<= 1) {
        int v = (t >= off) ? s[t - off] : 0;
        __syncthreads();
        s[t] += v;
        __syncthreads();
    }
    if (t < SB) boff[t] = (t == 0) ? 0 : s[t - 1];
    if (t == 0) row_start[NN] = s[SB - 1];  // = NE
}

// ------- scan phase 3: add block offsets; init cur = row_start -------
__global__ __launch_bounds__(256) void k_scan3(int* __restrict__ row_start,
                                               const int* __restrict__ boff,
                                               int* __restrict__ cur) {
    const int b = blockIdx.x;
    const int i0 = b * 1024 + threadIdx.x * 4;
    const int o = boff[b];
#pragma unroll
    for (int k = 0; k < 4; ++k) {
        int i = i0 + k;
        if (i < NN) {
            int v = row_start[i] + o;
            row_start[i] = v;
            cur[i] = v;
        }
    }
}

// ------- CSR build: scatter src + log1p(edge_attr) into dst-sorted order -------
// cur pre-initialized to row_start, so pos comes from one atomic.
// e5s rows padded to 8 floats (32 B) for aligned float4 loads in k_agg.
__global__ void k_scatter(const int* __restrict__ ei, const float* __restrict__ ea,
                          int* __restrict__ cur, int* __restrict__ srcs,
                          float* __restrict__ e5s) {
    int e = blockIdx.x * blockDim.x + threadIdx.x;
    if (e < NE) {
        int d = ei[NE + e];
        int pos = atomicAdd(&cur[d], 1);
        srcs[pos] = ei[e];
        float4 v4;
        v4.x = __logf(ea[e * 5 + 0] + 1.f);
        v4.y = __logf(ea[e * 5 + 1] + 1.f);
        v4.z = __logf(ea[e * 5 + 2] + 1.f);
        v4.w = __logf(ea[e * 5 + 3] + 1.f);
        *(float4*)(e5s + (size_t)pos * 8) = v4;
        e5s[(size_t)pos * 8 + 4] = __logf(ea[e * 5 + 4] + 1.f);
    }
}

// ---------------- pair GEMM: O0 = h@W0+B0, O1 = h@W1+B1 ----------------
// lane = out col; weights VGPR-resident; x rows via wave-uniform s_loads.
template <int DIN, int NB>
__global__ __launch_bounds__(256) void k_pg(
    const float* __restrict__ h,
    const float* __restrict__ W0, const float* __restrict__ B0,
    const float* __restrict__ W1, const float* __restrict__ B1,
    float* __restrict__ O0, int ldo0, float* __restrict__ O1, int ldo1) {
    const int lane = threadIdx.x & 63;
    const int wid = (blockIdx.x * blockDim.x + threadIdx.x) >> 6;
    const int nw = (gridDim.x * blockDim.x) >> 6;
    float w0[DIN], w1[DIN];
#pragma unroll
    for (int j = 0; j < DIN; ++j) {
        w0[j] = W0[j * 64 + lane];
        w1[j] = W1[j * 64 + lane];
    }
    const float b0 = B0[lane], b1 = B1[lane];
    const int nbatch = NN / NB;  // 50000 divisible by NB in {1,2,4}
    for (int b = wid; b < nbatch; b += nw) {
        const int n0 = __builtin_amdgcn_readfirstlane(b * NB);
        const float* hp = h + (size_t)n0 * DIN;
        float a0[NB], a1[NB];
#pragma unroll
        for (int n = 0; n < NB; ++n) {
            a0[n] = b0;
            a1[n] = b1;
        }
#pragma unroll
        for (int n = 0; n < NB; ++n) {
#pragma unroll
            for (int j = 0; j < DIN; ++j) {
                const float xv = hp[n * DIN + j];  // scalar (uniform) load
                a0[n] = fmaf(xv, w0[j], a0[n]);
                a1[n] = fmaf(xv, w1[j], a1[n]);
            }
        }
#pragma unroll
        for (int n = 0; n < NB; ++n) {
            O0[(size_t)(n0 + n) * ldo0 + lane] = a0[n];
            O1[(size_t)(n0 + n) * ldo1 + lane] = a1[n];
        }
    }
}

// ---------------- per-dst-node online-softmax aggregation ----------------
// One wave per dst node; 4 edges/iter. g = lane>>4 (edge slot), t = lane&15.
// Algebra: q.(k+ee) = q.k + g5.e5  (g5 = wE^T q, 5-dim);
//          sum a(v+ee) = sum a v + wE^T (sum a e5).
// Software pipeline: srcs/e5 prefetched 1 iter ahead; kv gather issued 1 ahead.
__global__ __launch_bounds__(256) void k_agg(
    const float* __restrict__ q, const float* __restrict__ kv,
    const float* __restrict__ sk, const float* __restrict__ e5s,
    const int* __restrict__ srcs, const float* __restrict__ wE,
    const int* __restrict__ row_start, float* __restrict__ hout) {
    const int lane = threadIdx.x & 63;
    const int g = lane >> 4, t = lane & 15;
    const int node = __builtin_amdgcn_readfirstlane(blockIdx.x * 4 + (threadIdx.x >> 6));
    if (node >= NN) return;
    const int beg = row_start[node], end = row_start[node + 1];
    const float4 s4 = *(const float4*)(sk + (size_t)node * 64 + t * 4);
    if (beg == end) {
        if (g == 0) *(float4*)(hout + (size_t)node * 64 + t * 4) = s4;
        return;
    }
    float4 we4[5];
#pragma unroll
    for (int c = 0; c < 5; ++c) we4[c] = *(const float4*)(wE + c * 64 + t * 4);
    const float4 q4 = *(const float4*)(q + (size_t)node * 64 + t * 4);
    // g5[c] = dot64(q, wE col c), in-group 16-lane reduce (identical across groups)
    float g5[5];
#pragma unroll
    for (int c = 0; c < 5; ++c) {
        float d = q4.x * we4[c].x;
        d = fmaf(q4.y, we4[c].y, d);
        d = fmaf(q4.z, we4[c].z, d);
        d = fmaf(q4.w, we4[c].w, d);
        d += __shfl_xor(d, 1);
        d += __shfl_xor(d, 2);
        d += __shfl_xor(d, 4);
        d += __shfl_xor(d, 8);
        g5[c] = d;
    }
    float m = -1e30f, l = 0.f;
    float4 accv = {0.f, 0.f, 0.f, 0.f};
    float a50 = 0.f, a51 = 0.f, a52 = 0.f, a53 = 0.f, a54 = 0.f;
    // pipeline preamble: src/e5 for first iter, kv issued immediately after
    int pp = (beg + g < end) ? beg + g : beg;
    int scur = srcs[pp];
    float4 ecur = *(const float4*)(e5s + (size_t)pp * 8);
    float e4cur = e5s[(size_t)pp * 8 + 4];
    const float* kvp0 = kv + (size_t)scur * 128 + t * 4;
    float4 k4 = *(const float4*)(kvp0);
    float4 v4 = *(const float4*)(kvp0 + 64);
    for (int p = beg; p < end; p += 4) {
        // prefetch srcs/e5 for next iteration (address-independent)
        const int pn = p + 4;
        const int npp = (pn < end) ? ((pn + g < end) ? pn + g : beg) : beg;
        const int nsrc = srcs[npp];
        const float4 ne = *(const float4*)(e5s + (size_t)npp * 8);
        const float ne4 = e5s[(size_t)npp * 8 + 4];
        // compute with current edge (k4/v4 already in flight)
        const bool act = (p + g) < end;
        float d5 = g5[0] * ecur.x;
        d5 = fmaf(g5[1], ecur.y, d5);
        d5 = fmaf(g5[2], ecur.z, d5);
        d5 = fmaf(g5[3], ecur.w, d5);
        d5 = fmaf(g5[4], e4cur, d5);
        float d = q4.x * k4.x;
        d = fmaf(q4.y, k4.y, d);
        d = fmaf(q4.z, k4.z, d);
        d = fmaf(q4.w, k4.w, d);
        d += __shfl_xor(d, 1);
        d += __shfl_xor(d, 2);
        d += __shfl_xor(d, 4);
        d += __shfl_xor(d, 8);
        const float la = act ? (d + d5) * 0.125f : -1e30f;
        const float lb = __shfl_xor(la, 16);
        const float lc = __shfl_xor(la, 32);
        const float ld = __shfl_xor(lb, 32);
        const float nm = fmaxf(fmaxf(fmaxf(la, lb), fmaxf(lc, ld)), m);
        const float scl = __expf(m - nm);
        const float pa = __expf(la - nm);
        const float pb = __expf(lb - nm);
        const float pc = __expf(lc - nm);
        const float pd = __expf(ld - nm);
        l = fmaf(l, scl, (pa + pb) + (pc + pd));
        accv.x = fmaf(accv.x, scl, pa * v4.x);
        accv.y = fmaf(accv.y, scl, pa * v4.y);
        accv.z = fmaf(accv.z, scl, pa * v4.z);
        accv.w = fmaf(accv.w, scl, pa * v4.w);
        a50 = fmaf(a50, scl, pa * ecur.x);
        a51 = fmaf(a51, scl, pa * ecur.y);
        a52 = fmaf(a52, scl, pa * ecur.z);
        a53 = fmaf(a53, scl, pa * ecur.w);
        a54 = fmaf(a54, scl, pa * e4cur);
        m = nm;
        // issue kv gather for next iter (nsrc has landed by now)
        const float* kvpn = kv + (size_t)nsrc * 128 + t * 4;
        k4 = *(const float4*)(kvpn);
        v4 = *(const float4*)(kvpn + 64);
        ecur = ne;
        e4cur = ne4;
        scur = nsrc;
    }
    // cross-group reduction (each group holds its own edges' partials)
    accv.x += __shfl_xor(accv.x, 16);
    accv.y += __shfl_xor(accv.y, 16);
    accv.z += __shfl_xor(accv.z, 16);
    accv.w += __shfl_xor(accv.w, 16);
    accv.x += __shfl_xor(accv.x, 32);
    accv.y += __shfl_xor(accv.y, 32);
    accv.z += __shfl_xor(accv.z, 32);
    accv.w += __shfl_xor(accv.w, 32);
    a50 += __shfl_xor(a50, 16); a50 += __shfl_xor(a50, 32);
    a51 += __shfl_xor(a51, 16); a51 += __shfl_xor(a51, 32);
    a52 += __shfl_xor(a52, 16); a52 += __shfl_xor(a52, 32);
    a53 += __shfl_xor(a53, 16); a53 += __shfl_xor(a53, 32);
    a54 += __shfl_xor(a54, 16); a54 += __shfl_xor(a54, 32);
    // out = sk + (accv + wE^T acc5) / l
    float4 t4;
    t4.x = fmaf(a50, we4[0].x, accv.x);
    t4.y = fmaf(a50, we4[0].y, accv.y);
    t4.z = fmaf(a50, we4[0].z, accv.z);
    t4.w = fmaf(a50, we4[0].w, accv.w);
    t4.x = fmaf(a51, we4[1].x, t4.x);
    t4.y = fmaf(a51, we4[1].y, t4.y);
    t4.z = fmaf(a51, we4[1].z, t4.z);
    t4.w = fmaf(a51, we4[1].w, t4.w);
    t4.x = fmaf(a52, we4[2].x, t4.x);
    t4.y = fmaf(a52, we4[2].y, t4.y);
    t4.z = fmaf(a52, we4[2].z, t4.z);
    t4.w = fmaf(a52, we4[2].w, t4.w);
    t4.x = fmaf(a53, we4[3].x, t4.x);
    t4.y = fmaf(a53, we4[3].y, t4.y);
    t4.z = fmaf(a53, we4[3].z, t4.z);
    t4.w = fmaf(a53, we4[3].w, t4.w);
    t4.x = fmaf(a54, we4[4].x, t4.x);
    t4.y = fmaf(a54, we4[4].y, t4.y);
    t4.z = fmaf(a54, we4[4].z, t4.z);
    t4.w = fmaf(a54, we4[4].w, t4.w);
    const float rl = 1.f / l;
    float4 o;
    o.x = fmaf(t4.x, rl, s4.x);
    o.y = fmaf(t4.y, rl, s4.y);
    o.z = fmaf(t4.z, rl, s4.z);
    o.w = fmaf(t4.w, rl, s4.w);
    if (g == 0) *(float4*)(hout + (size_t)node * 64 + t * 4) = o;
}

// ---------------- final linear HID -> 1 ----------------
__global__ __launch_bounds__(256) void k_final(const float* __restrict__ h,
                                               const float* __restrict__ lw,
                                               const float* __restrict__ lb,
                                               float* __restrict__ out) {
    const int lane = threadIdx.x & 63;
    int node = blockIdx.x * 4 + (threadIdx.x >> 6);
    if (node >= NN) return;
    float t = h[(size_t)node * 64 + lane] * lw[lane];
#pragma unroll
    for (int off = 32; off > 0; off >>= 1) t += __shfl_xor(t, off, 64);
    if (lane == 0) out[node] = t + lb[0];
}

extern "C" void kernel_launch(void* const* d_in, const int* in_sizes, int n_in,
                              void* d_out, int out_size, void* d_ws, size_t ws_size,
                              hipStream_t stream) {
    const float* x = (const float*)d_in[0];
    const int* ei = (const int*)d_in[1];  // int32 per harness contract
    const float* ea = (const float*)d_in[2];
    const float* w1q = (const float*)d_in[3];
    const float* b1q = (const float*)d_in[4];
    const float* w1k = (const float*)d_in[5];
    const float* b1k = (const float*)d_in[6];
    const float* w1v = (const float*)d_in[7];
    const float* b1v = (const float*)d_in[8];
    const float* w1e = (const float*)d_in[9];
    const float* w1s = (const float*)d_in[10];
    const float* b1s = (const float*)d_in[11];
    const float* wq = (const float*)d_in[12];
    const float* bq = (const float*)d_in[13];
    const float* wk = (const float*)d_in[14];
    const float* bk = (const float*)d_in[15];
    const float* wv = (const float*)d_in[16];
    const float* bv = (const float*)d_in[17];
    const float* we = (const float*)d_in[18];
    const float* ws = (const float*)d_in[19];
    const float* bs = (const float*)d_in[20];
    const float* lw = (const float*)d_in[21];
    const float* lb = (const float*)d_in[22];

    // ---- workspace carve (256B aligned), ~95 MB ----
    uintptr_t p = (uintptr_t)d_ws;
    auto alloc = [&](size_t bytes) -> void* {
        void* r = (void*)p;
        p += (bytes + 255) & ~(size_t)255;
        return r;
    };
    float* e5s = (float*)alloc((size_t)NE * 8 * 4);    // 25.6 MB, dst-sorted padded rows
    float* h0 = (float*)alloc((size_t)NN * 10 * 4);    // 2 MB
    float* hb = (float*)alloc((size_t)NN * HD * 4);    // 12.8 MB
    float* kvb = (float*)alloc((size_t)NN * 128 * 4);  // 25.6 MB interleaved k|v
    float* qb = (float*)alloc((size_t)NN * HD * 4);
    float* sb = (float*)alloc((size_t)NN * HD * 4);
    int* srcs = (int*)alloc((size_t)NE * 4);           // 3.2 MB dst-sorted src ids
    int* row_start = (int*)alloc((size_t)(NN + 1) * 4);
    int* cnt = (int*)alloc((size_t)NN * 4);
    int* cur = (int*)alloc((size_t)NN * 4);
    int* bsum = (int*)alloc((size_t)SB * 4);
    int* boff = (int*)alloc((size_t)SB * 4);

    // ---- preprocess (once per call) ----
    hipMemsetAsync(cnt, 0, (size_t)NN * 4, stream);
    k_log1p<<<(NN * 10 + 255) / 256, 256, 0, stream>>>(x, h0, NN * 10);
    k_hist<<<(NE + 255) / 256, 256, 0, stream>>>(ei, cnt);
    k_scan1<<<SB, 256, 0, stream>>>(cnt, row_start, bsum);
    k_scan2<<<1, 64, 0, stream>>>(bsum, boff, row_start);
    k_scan3<<<SB, 256, 0, stream>>>(row_start, boff, cur);
    k_scatter<<<(NE + 255) / 256, 256, 0, stream>>>(ei, ea, cur, srcs, e5s);

    const int gg = 512;                 // gemm grid (2048 waves)
    const int agg_grid = (NN + 3) / 4;  // 12500

    // ---- layer 1 (DIN=10, 4 nodes/iter) ----
    k_pg<10, 4><<<gg, 256, 0, stream>>>(h0, w1k, b1k, w1v, b1v, kvb, 128, kvb + 64, 128);
    k_pg<10, 4><<<gg, 256, 0, stream>>>(h0, w1q, b1q, w1s, b1s, qb, 64, sb, 64);
    k_agg<<<agg_grid, 256, 0, stream>>>(qb, kvb, sb, e5s, srcs, w1e, row_start, hb);

    // ---- layers 2..6 (DIN=64, 2 nodes/iter) ----
    for (int i = 0; i < 5; ++i) {
        k_pg<64, 2><<<gg, 256, 0, stream>>>(hb, wk + i * 4096, bk + i * 64,
                                            wv + i * 4096, bv + i * 64, kvb, 128, kvb + 64, 128);
        k_pg<64, 2><<<gg, 256, 0, stream>>>(hb, wq + i * 4096, bq + i * 64,
                                            ws + i * 4096, bs + i * 64, qb, 64, sb, 64);
        k_agg<<<agg_grid, 256, 0, stream>>>(qb, kvb, sb, e5s, srcs, we + i * 320, row_start, hb);
    }

    // ---- final linear ----
    k_final<<<agg_grid, 256, 0, stream>>>(hb, lw, lb, (float*)d_out);
}

// Round 5
// 849.632 us; speedup vs baseline: 2.8602x; 1.0343x over previous
//
#include <hip/hip_runtime.h>
#include <cstdint>
#include <cstddef>

#define NN 50000
#define NE 800000
#define HD 64
#define SB 49  // scan blocks = ceil(50000/1024)

// ---------------- elementwise log1p (node features) ----------------
__global__ void k_log1p(const float* __restrict__ in, float* __restrict__ out, int n) {
    int i = blockIdx.x * blockDim.x + threadIdx.x;
    if (i < n) out[i] = __logf(in[i] + 1.0f);
}

// ---------------- CSR build: histogram ----------------
__global__ void k_hist(const int* __restrict__ ei, int* __restrict__ cnt) {
    int e = blockIdx.x * blockDim.x + threadIdx.x;
    if (e < NE) atomicAdd(&cnt[ei[NE + e]], 1);
}

// ------- hierarchical scan, phase 1: per-block local exclusive scan -------
__global__ __launch_bounds__(256) void k_scan1(const int* __restrict__ cnt,
                                               int* __restrict__ row_start,
                                               int* __restrict__ bsum) {
    __shared__ int ssum[256];
    const int tid = threadIdx.x, b = blockIdx.x;
    const int i0 = b * 1024 + tid * 4;
    int c0 = 0, c1 = 0, c2 = 0, c3 = 0;
    if (i0 + 3 < NN) {
        const int4 c = *(const int4*)(cnt + i0);
        c0 = c.x; c1 = c.y; c2 = c.z; c3 = c.w;
    } else {
        if (i0 + 0 < NN) c0 = cnt[i0 + 0];
        if (i0 + 1 < NN) c1 = cnt[i0 + 1];
        if (i0 + 2 < NN) c2 = cnt[i0 + 2];
        if (i0 + 3 < NN) c3 = cnt[i0 + 3];
    }
    ssum[tid] = c0 + c1 + c2 + c3;
    __syncthreads();
    for (int off = 1; off < 256; off <<= 1) {
        int v = (tid >= off) ? ssum[tid - off] : 0;
        __syncthreads();
        ssum[tid] += v;
        __syncthreads();
    }
    int ex = (tid == 0) ? 0 : ssum[tid - 1];
    if (i0 + 0 < NN) row_start[i0 + 0] = ex;
    ex += c0;
    if (i0 + 1 < NN) row_start[i0 + 1] = ex;
    ex += c1;
    if (i0 + 2 < NN) row_start[i0 + 2] = ex;
    ex += c2;
    if (i0 + 3 < NN) row_start[i0 + 3] = ex;
    if (tid == 255) bsum[b] = ssum[255];
}

// ------- scan phase 2: scan the 49 block sums -------
__global__ __launch_bounds__(64) void k_scan2(const int* __restrict__ bsum,
                                              int* __restrict__ boff,
                                              int* __restrict__ row_start) {
    __shared__ int s[64];
    const int t = threadIdx.x;
    s[t] = (t < SB) ? bsum[t] : 0;
    __syncthreads();
    for (int off = 1; off < 64; off <<= 1) {
        int v = (t >= off) ? s[t - off] : 0;
        __syncthreads();
        s[t] += v;
        __syncthreads();
    }
    if (t < SB) boff[t] = (t == 0) ? 0 : s[t - 1];
    if (t == 0) row_start[NN] = s[SB - 1];  // = NE
}

// ------- scan phase 3: add block offsets; init cur = row_start -------
__global__ __launch_bounds__(256) void k_scan3(int* __restrict__ row_start,
                                               const int* __restrict__ boff,
                                               int* __restrict__ cur) {
    const int b = blockIdx.x;
    const int i0 = b * 1024 + threadIdx.x * 4;
    const int o = boff[b];
#pragma unroll
    for (int k = 0; k < 4; ++k) {
        int i = i0 + k;
        if (i < NN) {
            int v = row_start[i] + o;
            row_start[i] = v;
            cur[i] = v;
        }
    }
}

// ------- CSR scatter: row = [e0,e1,e2,e3, e4, src_bits, 0, 0] dst-sorted -------
__global__ void k_scatter(const int* __restrict__ ei, const float* __restrict__ ea,
                          int* __restrict__ cur, float* __restrict__ e5s) {
    int e = blockIdx.x * blockDim.x + threadIdx.x;
    if (e < NE) {
        int d = ei[NE + e];
        int pos = atomicAdd(&cur[d], 1);
        float4 lo;
        lo.x = __logf(ea[e * 5 + 0] + 1.f);
        lo.y = __logf(ea[e * 5 + 1] + 1.f);
        lo.z = __logf(ea[e * 5 + 2] + 1.f);
        lo.w = __logf(ea[e * 5 + 3] + 1.f);
        float4 hi;
        hi.x = __logf(ea[e * 5 + 4] + 1.f);
        hi.y = __int_as_float(ei[e]);
        hi.z = 0.f;
        hi.w = 0.f;
        *(float4*)(e5s + (size_t)pos * 8) = lo;
        *(float4*)(e5s + (size_t)pos * 8 + 4) = hi;
    }
}

// ---------------- pair GEMM DIN=10 (layer 1): scalar-load path ----------------
template <int DIN, int NB>
__global__ __launch_bounds__(256) void k_pg(
    const float* __restrict__ h,
    const float* __restrict__ W0, const float* __restrict__ B0,
    const float* __restrict__ W1, const float* __restrict__ B1,
    float* __restrict__ O0, int ldo0, float* __restrict__ O1, int ldo1) {
    const int lane = threadIdx.x & 63;
    const int wid = (blockIdx.x * blockDim.x + threadIdx.x) >> 6;
    const int nw = (gridDim.x * blockDim.x) >> 6;
    float w0[DIN], w1[DIN];
#pragma unroll
    for (int j = 0; j < DIN; ++j) {
        w0[j] = W0[j * 64 + lane];
        w1[j] = W1[j * 64 + lane];
    }
    const float b0 = B0[lane], b1 = B1[lane];
    const int nbatch = NN / NB;
    for (int b = wid; b < nbatch; b += nw) {
        const int n0 = __builtin_amdgcn_readfirstlane(b * NB);
        const float* hp = h + (size_t)n0 * DIN;
        float a0[NB], a1[NB];
#pragma unroll
        for (int n = 0; n < NB; ++n) {
            a0[n] = b0;
            a1[n] = b1;
        }
#pragma unroll
        for (int n = 0; n < NB; ++n) {
#pragma unroll
            for (int j = 0; j < DIN; ++j) {
                const float xv = hp[n * DIN + j];
                a0[n] = fmaf(xv, w0[j], a0[n]);
                a1[n] = fmaf(xv, w1[j], a1[n]);
            }
        }
#pragma unroll
        for (int n = 0; n < NB; ++n) {
            O0[(size_t)(n0 + n) * ldo0 + lane] = a0[n];
            O1[(size_t)(n0 + n) * ldo1 + lane] = a1[n];
        }
    }
}

// ---------------- pair GEMM DIN=64: LDS-broadcast path ----------------
// Weights VGPR-resident (lane = out col). 4 nodes/wave-iter: coalesced float4
// global load -> per-wave LDS tile -> ds_read_b128 broadcast -> FMA.
__global__ __launch_bounds__(256) void k_pg64(
    const float* __restrict__ h,
    const float* __restrict__ W0, const float* __restrict__ B0,
    const float* __restrict__ W1, const float* __restrict__ B1,
    float* __restrict__ O0, int ldo0, float* __restrict__ O1, int ldo1) {
    __shared__ float xs[4][256];
    const int lane = threadIdx.x & 63, w = threadIdx.x >> 6;
    float w0[64], w1[64];
#pragma unroll
    for (int j = 0; j < 64; ++j) {
        w0[j] = W0[j * 64 + lane];
        w1[j] = W1[j * 64 + lane];
    }
    const float b0 = B0[lane], b1 = B1[lane];
    const int wid = blockIdx.x * 4 + w;
    const int nw = gridDim.x * 4;
    const int nquad = NN / 4;  // 12500
    for (int quad = wid; quad < nquad; quad += nw) {
        const float4 hv = *(const float4*)(h + (size_t)quad * 256 + lane * 4);
        *(float4*)(&xs[w][lane * 4]) = hv;  // wave-synchronous LDS staging
        float a0[4], a1[4];
#pragma unroll
        for (int n = 0; n < 4; ++n) {
            a0[n] = b0;
            a1[n] = b1;
        }
#pragma unroll
        for (int n = 0; n < 4; ++n) {
#pragma unroll
            for (int jq = 0; jq < 16; ++jq) {
                const float4 xv = *(const float4*)(&xs[w][n * 64 + jq * 4]);  // broadcast
                a0[n] = fmaf(xv.x, w0[jq * 4 + 0], a0[n]);
                a1[n] = fmaf(xv.x, w1[jq * 4 + 0], a1[n]);
                a0[n] = fmaf(xv.y, w0[jq * 4 + 1], a0[n]);
                a1[n] = fmaf(xv.y, w1[jq * 4 + 1], a1[n]);
                a0[n] = fmaf(xv.z, w0[jq * 4 + 2], a0[n]);
                a1[n] = fmaf(xv.z, w1[jq * 4 + 2], a1[n]);
                a0[n] = fmaf(xv.w, w0[jq * 4 + 3], a0[n]);
                a1[n] = fmaf(xv.w, w1[jq * 4 + 3], a1[n]);
            }
        }
#pragma unroll
        for (int n = 0; n < 4; ++n) {
            O0[(size_t)(quad * 4 + n) * ldo0 + lane] = a0[n];
            O1[(size_t)(quad * 4 + n) * ldo1 + lane] = a1[n];
        }
    }
}

// ---------------- per-dst-node online-softmax aggregation, 8 edges/iter ----------------
// One wave per dst node. g = lane>>3 (edge slot, 8), t = lane&7 (8 feats each).
// logit = (q.k + g5.e5)/8 ; out = sk + (accv + wE^T a5)/l.
// Only 2 exps/iter: own-slot p + rescale; Sum-p and max via cross-group butterflies.
__global__ __launch_bounds__(256) void k_agg(
    const float* __restrict__ q, const float* __restrict__ kv,
    const float* __restrict__ sk, const float* __restrict__ e5s,
    const float* __restrict__ wE, const int* __restrict__ row_start,
    float* __restrict__ hout) {
    const int lane = threadIdx.x & 63;
    const int g = lane >> 3, t = lane & 7;
    const int node = __builtin_amdgcn_readfirstlane(blockIdx.x * 4 + (threadIdx.x >> 6));
    if (node >= NN) return;
    const int beg = row_start[node], end = row_start[node + 1];
    const float4 sa = *(const float4*)(sk + (size_t)node * 64 + t * 8);
    const float4 sb4 = *(const float4*)(sk + (size_t)node * 64 + t * 8 + 4);
    if (beg == end) {
        if (g == 0) {
            *(float4*)(hout + (size_t)node * 64 + t * 8) = sa;
            *(float4*)(hout + (size_t)node * 64 + t * 8 + 4) = sb4;
        }
        return;
    }
    float4 wa[5], wb[5];
#pragma unroll
    for (int c = 0; c < 5; ++c) {
        wa[c] = *(const float4*)(wE + c * 64 + t * 8);
        wb[c] = *(const float4*)(wE + c * 64 + t * 8 + 4);
    }
    const float4 qa = *(const float4*)(q + (size_t)node * 64 + t * 8);
    const float4 qb = *(const float4*)(q + (size_t)node * 64 + t * 8 + 4);
    // g5[c] = dot64(q, wE row c): 8-lane in-group butterfly (uniform per group)
    float g5[5];
#pragma unroll
    for (int c = 0; c < 5; ++c) {
        float d = qa.x * wa[c].x;
        d = fmaf(qa.y, wa[c].y, d);
        d = fmaf(qa.z, wa[c].z, d);
        d = fmaf(qa.w, wa[c].w, d);
        d = fmaf(qb.x, wb[c].x, d);
        d = fmaf(qb.y, wb[c].y, d);
        d = fmaf(qb.z, wb[c].z, d);
        d = fmaf(qb.w, wb[c].w, d);
        d += __shfl_xor(d, 1);
        d += __shfl_xor(d, 2);
        d += __shfl_xor(d, 4);
        g5[c] = d;
    }
    float m = -1e30f, l = 0.f;
    float4 aca = {0.f, 0.f, 0.f, 0.f}, acb = {0.f, 0.f, 0.f, 0.f};
    float a5[5] = {0.f, 0.f, 0.f, 0.f, 0.f};
    // pipeline preamble
    int pp = (beg + g < end) ? beg + g : beg;
    float4 elo = *(const float4*)(e5s + (size_t)pp * 8);
    float4 ehi = *(const float4*)(e5s + (size_t)pp * 8 + 4);
    {
        const int scur = __float_as_int(ehi.y);
        const float* kp = kv + (size_t)scur * 128 + t * 8;
        // fallthrough into loop with ka..vb live
        float4 ka = *(const float4*)(kp);
        float4 kb = *(const float4*)(kp + 4);
        float4 va = *(const float4*)(kp + 64);
        float4 vb = *(const float4*)(kp + 68);
        for (int p = beg; p < end; p += 8) {
            const int pn = p + 8;
            const int npp = (pn + g < end) ? pn + g : beg;
            const float4 nelo = *(const float4*)(e5s + (size_t)npp * 8);
            const float4 nehi = *(const float4*)(e5s + (size_t)npp * 8 + 4);
            const bool act = (p + g) < end;
            float d5 = g5[0] * elo.x;
            d5 = fmaf(g5[1], elo.y, d5);
            d5 = fmaf(g5[2], elo.z, d5);
            d5 = fmaf(g5[3], elo.w, d5);
            d5 = fmaf(g5[4], ehi.x, d5);
            float d = qa.x * ka.x;
            d = fmaf(qa.y, ka.y, d);
            d = fmaf(qa.z, ka.z, d);
            d = fmaf(qa.w, ka.w, d);
            d = fmaf(qb.x, kb.x, d);
            d = fmaf(qb.y, kb.y, d);
            d = fmaf(qb.z, kb.z, d);
            d = fmaf(qb.w, kb.w, d);
            d += __shfl_xor(d, 1);
            d += __shfl_xor(d, 2);
            d += __shfl_xor(d, 4);
            const float la = act ? (d + d5) * 0.125f : -1e30f;
            float mx = fmaxf(la, __shfl_xor(la, 8));
            mx = fmaxf(mx, __shfl_xor(mx, 16));
            mx = fmaxf(mx, __shfl_xor(mx, 32));
            const float nm = fmaxf(mx, m);
            const float scl = __expf(m - nm);
            const float pa = __expf(la - nm);  // own slot (0 if inactive)
            float ps = pa + __shfl_xor(pa, 8);
            ps += __shfl_xor(ps, 16);
            ps += __shfl_xor(ps, 32);
            l = fmaf(l, scl, ps);
            aca.x = fmaf(aca.x, scl, pa * va.x);
            aca.y = fmaf(aca.y, scl, pa * va.y);
            aca.z = fmaf(aca.z, scl, pa * va.z);
            aca.w = fmaf(aca.w, scl, pa * va.w);
            acb.x = fmaf(acb.x, scl, pa * vb.x);
            acb.y = fmaf(acb.y, scl, pa * vb.y);
            acb.z = fmaf(acb.z, scl, pa * vb.z);
            acb.w = fmaf(acb.w, scl, pa * vb.w);
            a5[0] = fmaf(a5[0], scl, pa * elo.x);
            a5[1] = fmaf(a5[1], scl, pa * elo.y);
            a5[2] = fmaf(a5[2], scl, pa * elo.z);
            a5[3] = fmaf(a5[3], scl, pa * elo.w);
            a5[4] = fmaf(a5[4], scl, pa * ehi.x);
            m = nm;
            // advance pipeline: issue next kv gather
            const int nsrc = __float_as_int(nehi.y);
            const float* kpn = kv + (size_t)nsrc * 128 + t * 8;
            ka = *(const float4*)(kpn);
            kb = *(const float4*)(kpn + 4);
            va = *(const float4*)(kpn + 64);
            vb = *(const float4*)(kpn + 68);
            elo = nelo;
            ehi = nehi;
        }
    }
    // cross-group reduction of accumulators
#pragma unroll
    for (int s = 8; s <= 32; s <<= 1) {
        aca.x += __shfl_xor(aca.x, s);
        aca.y += __shfl_xor(aca.y, s);
        aca.z += __shfl_xor(aca.z, s);
        aca.w += __shfl_xor(aca.w, s);
        acb.x += __shfl_xor(acb.x, s);
        acb.y += __shfl_xor(acb.y, s);
        acb.z += __shfl_xor(acb.z, s);
        acb.w += __shfl_xor(acb.w, s);
        a5[0] += __shfl_xor(a5[0], s);
        a5[1] += __shfl_xor(a5[1], s);
        a5[2] += __shfl_xor(a5[2], s);
        a5[3] += __shfl_xor(a5[3], s);
        a5[4] += __shfl_xor(a5[4], s);
    }
    // fold edge-feature accumulator back through wE
    float4 ta = aca, tb = acb;
#pragma unroll
    for (int c = 0; c < 5; ++c) {
        ta.x = fmaf(a5[c], wa[c].x, ta.x);
        ta.y = fmaf(a5[c], wa[c].y, ta.y);
        ta.z = fmaf(a5[c], wa[c].z, ta.z);
        ta.w = fmaf(a5[c], wa[c].w, ta.w);
        tb.x = fmaf(a5[c], wb[c].x, tb.x);
        tb.y = fmaf(a5[c], wb[c].y, tb.y);
        tb.z = fmaf(a5[c], wb[c].z, tb.z);
        tb.w = fmaf(a5[c], wb[c].w, tb.w);
    }
    const float rl = 1.f / l;
    float4 oa, ob;
    oa.x = fmaf(ta.x, rl, sa.x);
    oa.y = fmaf(ta.y, rl, sa.y);
    oa.z = fmaf(ta.z, rl, sa.z);
    oa.w = fmaf(ta.w, rl, sa.w);
    ob.x = fmaf(tb.x, rl, sb4.x);
    ob.y = fmaf(tb.y, rl, sb4.y);
    ob.z = fmaf(tb.z, rl, sb4.z);
    ob.w = fmaf(tb.w, rl, sb4.w);
    if (g == 0) {
        *(float4*)(hout + (size_t)node * 64 + t * 8) = oa;
        *(float4*)(hout + (size_t)node * 64 + t * 8 + 4) = ob;
    }
}

// ---------------- final linear HID -> 1 ----------------
__global__ __launch_bounds__(256) void k_final(const float* __restrict__ h,
                                               const float* __restrict__ lw,
                                               const float* __restrict__ lb,
                                               float* __restrict__ out) {
    const int lane = threadIdx.x & 63;
    int node = blockIdx.x * 4 + (threadIdx.x >> 6);
    if (node >= NN) return;
    float t = h[(size_t)node * 64 + lane] * lw[lane];
#pragma unroll
    for (int off = 32; off > 0; off >>= 1) t += __shfl_xor(t, off, 64);
    if (lane == 0) out[node] = t + lb[0];
}

extern "C" void kernel_launch(void* const* d_in, const int* in_sizes, int n_in,
                              void* d_out, int out_size, void* d_ws, size_t ws_size,
                              hipStream_t stream) {
    const float* x = (const float*)d_in[0];
    const int* ei = (const int*)d_in[1];
    const float* ea = (const float*)d_in[2];
    const float* w1q = (const float*)d_in[3];
    const float* b1q = (const float*)d_in[4];
    const float* w1k = (const float*)d_in[5];
    const float* b1k = (const float*)d_in[6];
    const float* w1v = (const float*)d_in[7];
    const float* b1v = (const float*)d_in[8];
    const float* w1e = (const float*)d_in[9];
    const float* w1s = (const float*)d_in[10];
    const float* b1s = (const float*)d_in[11];
    const float* wq = (const float*)d_in[12];
    const float* bq = (const float*)d_in[13];
    const float* wk = (const float*)d_in[14];
    const float* bk = (const float*)d_in[15];
    const float* wv = (const float*)d_in[16];
    const float* bv = (const float*)d_in[17];
    const float* we = (const float*)d_in[18];
    const float* ws = (const float*)d_in[19];
    const float* bs = (const float*)d_in[20];
    const float* lw = (const float*)d_in[21];
    const float* lb = (const float*)d_in[22];

    // ---- workspace carve (256B aligned), ~92 MB ----
    uintptr_t p = (uintptr_t)d_ws;
    auto alloc = [&](size_t bytes) -> void* {
        void* r = (void*)p;
        p += (bytes + 255) & ~(size_t)255;
        return r;
    };
    float* e5s = (float*)alloc((size_t)NE * 8 * 4);    // 25.6 MB, dst-sorted rows (incl. src)
    float* h0 = (float*)alloc((size_t)NN * 10 * 4);    // 2 MB
    float* hb = (float*)alloc((size_t)NN * HD * 4);    // 12.8 MB
    float* kvb = (float*)alloc((size_t)NN * 128 * 4);  // 25.6 MB interleaved k|v
    float* qb = (float*)alloc((size_t)NN * HD * 4);
    float* sb = (float*)alloc((size_t)NN * HD * 4);
    int* row_start = (int*)alloc((size_t)(NN + 1) * 4);
    int* cnt = (int*)alloc((size_t)NN * 4);
    int* cur = (int*)alloc((size_t)NN * 4);
    int* bsum = (int*)alloc((size_t)SB * 4);
    int* boff = (int*)alloc((size_t)SB * 4);

    // ---- preprocess (once per call) ----
    hipMemsetAsync(cnt, 0, (size_t)NN * 4, stream);
    k_log1p<<<(NN * 10 + 255) / 256, 256, 0, stream>>>(x, h0, NN * 10);
    k_hist<<<(NE + 255) / 256, 256, 0, stream>>>(ei, cnt);
    k_scan1<<<SB, 256, 0, stream>>>(cnt, row_start, bsum);
    k_scan2<<<1, 64, 0, stream>>>(bsum, boff, row_start);
    k_scan3<<<SB, 256, 0, stream>>>(row_start, boff, cur);
    k_scatter<<<(NE + 255) / 256, 256, 0, stream>>>(ei, ea, cur, e5s);

    const int gg = 512;                 // gemm grid (2048 waves)
    const int agg_grid = (NN + 3) / 4;  // 12500

    // ---- layer 1 (DIN=10) ----
    k_pg<10, 4><<<gg, 256, 0, stream>>>(h0, w1k, b1k, w1v, b1v, kvb, 128, kvb + 64, 128);
    k_pg<10, 4><<<gg, 256, 0, stream>>>(h0, w1q, b1q, w1s, b1s, qb, 64, sb, 64);
    k_agg<<<agg_grid, 256, 0, stream>>>(qb, kvb, sb, e5s, w1e, row_start, hb);

    // ---- layers 2..6 (DIN=64) ----
    for (int i = 0; i < 5; ++i) {
        k_pg64<<<gg, 256, 0, stream>>>(hb, wk + i * 4096, bk + i * 64,
                                       wv + i * 4096, bv + i * 64, kvb, 128, kvb + 64, 128);
        k_pg64<<<gg, 256, 0, stream>>>(hb, wq + i * 4096, bq + i * 64,
                                       ws + i * 4096, bs + i * 64, qb, 64, sb, 64);
        k_agg<<<agg_grid, 256, 0, stream>>>(qb, kvb, sb, e5s, we + i * 320, row_start, hb);
    }

    // ---- final linear ----
    k_final<<<agg_grid, 256, 0, stream>>>(hb, lw, lb, (float*)d_out);
}

// Round 6
// 774.101 us; speedup vs baseline: 3.1393x; 1.0976x over previous
//
#include <hip/hip_runtime.h>
#include <cstdint>
#include <cstddef>

#define NN 50000
#define NE 800000
#define HD 64
#define SB 49  // scan blocks = ceil(50000/1024)

// ---------------- elementwise log1p (node features) ----------------
__global__ void k_log1p(const float* __restrict__ in, float* __restrict__ out, int n) {
    int i = blockIdx.x * blockDim.x + threadIdx.x;
    if (i < n) out[i] = __logf(in[i] + 1.0f);
}

// ---------------- CSR build: histogram ----------------
__global__ void k_hist(const int* __restrict__ ei, int* __restrict__ cnt) {
    int e = blockIdx.x * blockDim.x + threadIdx.x;
    if (e < NE) atomicAdd(&cnt[ei[NE + e]], 1);
}

// ------- hierarchical scan, phase 1: per-block local exclusive scan -------
__global__ __launch_bounds__(256) void k_scan1(const int* __restrict__ cnt,
                                               int* __restrict__ row_start,
                                               int* __restrict__ bsum) {
    __shared__ int ssum[256];
    const int tid = threadIdx.x, b = blockIdx.x;
    const int i0 = b * 1024 + tid * 4;
    int c0 = 0, c1 = 0, c2 = 0, c3 = 0;
    if (i0 + 3 < NN) {
        const int4 c = *(const int4*)(cnt + i0);
        c0 = c.x; c1 = c.y; c2 = c.z; c3 = c.w;
    } else {
        if (i0 + 0 < NN) c0 = cnt[i0 + 0];
        if (i0 + 1 < NN) c1 = cnt[i0 + 1];
        if (i0 + 2 < NN) c2 = cnt[i0 + 2];
        if (i0 + 3 < NN) c3 = cnt[i0 + 3];
    }
    ssum[tid] = c0 + c1 + c2 + c3;
    __syncthreads();
    for (int off = 1; off < 256; off <<= 1) {
        int v = (tid >= off) ? ssum[tid - off] : 0;
        __syncthreads();
        ssum[tid] += v;
        __syncthreads();
    }
    int ex = (tid == 0) ? 0 : ssum[tid - 1];
    if (i0 + 0 < NN) row_start[i0 + 0] = ex;
    ex += c0;
    if (i0 + 1 < NN) row_start[i0 + 1] = ex;
    ex += c1;
    if (i0 + 2 < NN) row_start[i0 + 2] = ex;
    ex += c2;
    if (i0 + 3 < NN) row_start[i0 + 3] = ex;
    if (tid == 255) bsum[b] = ssum[255];
}

// ------- scan phase 2: scan the 49 block sums -------
__global__ __launch_bounds__(64) void k_scan2(const int* __restrict__ bsum,
                                              int* __restrict__ boff,
                                              int* __restrict__ row_start) {
    __shared__ int s[64];
    const int t = threadIdx.x;
    s[t] = (t < SB) ? bsum[t] : 0;
    __syncthreads();
    for (int off = 1; off < 64; off <<= 1) {
        int v = (t >= off) ? s[t - off] : 0;
        __syncthreads();
        s[t] += v;
        __syncthreads();
    }
    if (t < SB) boff[t] = (t == 0) ? 0 : s[t - 1];
    if (t == 0) row_start[NN] = s[SB - 1];  // = NE
}

// ------- scan phase 3: add block offsets; init cur = row_start -------
__global__ __launch_bounds__(256) void k_scan3(int* __restrict__ row_start,
                                               const int* __restrict__ boff,
                                               int* __restrict__ cur) {
    const int b = blockIdx.x;
    const int i0 = b * 1024 + threadIdx.x * 4;
    const int o = boff[b];
#pragma unroll
    for (int k = 0; k < 4; ++k) {
        int i = i0 + k;
        if (i < NN) {
            int v = row_start[i] + o;
            row_start[i] = v;
            cur[i] = v;
        }
    }
}

// ------- CSR scatter: row = [e0,e1,e2,e3, e4, src_bits, 0, 0] dst-sorted -------
__global__ void k_scatter(const int* __restrict__ ei, const float* __restrict__ ea,
                          int* __restrict__ cur, float* __restrict__ e5s) {
    int e = blockIdx.x * blockDim.x + threadIdx.x;
    if (e < NE) {
        int d = ei[NE + e];
        int pos = atomicAdd(&cur[d], 1);
        float4 lo;
        lo.x = __logf(ea[e * 5 + 0] + 1.f);
        lo.y = __logf(ea[e * 5 + 1] + 1.f);
        lo.z = __logf(ea[e * 5 + 2] + 1.f);
        lo.w = __logf(ea[e * 5 + 3] + 1.f);
        float4 hi;
        hi.x = __logf(ea[e * 5 + 4] + 1.f);
        hi.y = __int_as_float(ei[e]);
        hi.z = 0.f;
        hi.w = 0.f;
        *(float4*)(e5s + (size_t)pos * 8) = lo;
        *(float4*)(e5s + (size_t)pos * 8 + 4) = hi;
    }
}

// ---------------- pair GEMM DIN=10 (layer 1): scalar-load path ----------------
template <int DIN, int NB>
__global__ __launch_bounds__(256) void k_pg(
    const float* __restrict__ h,
    const float* __restrict__ W0, const float* __restrict__ B0,
    const float* __restrict__ W1, const float* __restrict__ B1,
    float* __restrict__ O0, int ldo0, float* __restrict__ O1, int ldo1) {
    const int lane = threadIdx.x & 63;
    const int wid = (blockIdx.x * blockDim.x + threadIdx.x) >> 6;
    const int nw = (gridDim.x * blockDim.x) >> 6;
    float w0[DIN], w1[DIN];
#pragma unroll
    for (int j = 0; j < DIN; ++j) {
        w0[j] = W0[j * 64 + lane];
        w1[j] = W1[j * 64 + lane];
    }
    const float b0 = B0[lane], b1 = B1[lane];
    const int nbatch = NN / NB;
    for (int b = wid; b < nbatch; b += nw) {
        const int n0 = __builtin_amdgcn_readfirstlane(b * NB);
        const float* hp = h + (size_t)n0 * DIN;
        float a0[NB], a1[NB];
#pragma unroll
        for (int n = 0; n < NB; ++n) {
            a0[n] = b0;
            a1[n] = b1;
        }
#pragma unroll
        for (int n = 0; n < NB; ++n) {
#pragma unroll
            for (int j = 0; j < DIN; ++j) {
                const float xv = hp[n * DIN + j];
                a0[n] = fmaf(xv, w0[j], a0[n]);
                a1[n] = fmaf(xv, w1[j], a1[n]);
            }
        }
#pragma unroll
        for (int n = 0; n < NB; ++n) {
            O0[(size_t)(n0 + n) * ldo0 + lane] = a0[n];
            O1[(size_t)(n0 + n) * ldo1 + lane] = a1[n];
        }
    }
}

// ---------------- pair GEMM DIN=64: LDS-broadcast path ----------------
__global__ __launch_bounds__(256) void k_pg64(
    const float* __restrict__ h,
    const float* __restrict__ W0, const float* __restrict__ B0,
    const float* __restrict__ W1, const float* __restrict__ B1,
    float* __restrict__ O0, int ldo0, float* __restrict__ O1, int ldo1) {
    __shared__ float xs[4][256];
    const int lane = threadIdx.x & 63, w = threadIdx.x >> 6;
    float w0[64], w1[64];
#pragma unroll
    for (int j = 0; j < 64; ++j) {
        w0[j] = W0[j * 64 + lane];
        w1[j] = W1[j * 64 + lane];
    }
    const float b0 = B0[lane], b1 = B1[lane];
    const int wid = blockIdx.x * 4 + w;
    const int nw = gridDim.x * 4;
    const int nquad = NN / 4;  // 12500
    for (int quad = wid; quad < nquad; quad += nw) {
        const float4 hv = *(const float4*)(h + (size_t)quad * 256 + lane * 4);
        *(float4*)(&xs[w][lane * 4]) = hv;  // wave-synchronous LDS staging
        float a0[4], a1[4];
#pragma unroll
        for (int n = 0; n < 4; ++n) {
            a0[n] = b0;
            a1[n] = b1;
        }
#pragma unroll
        for (int n = 0; n < 4; ++n) {
#pragma unroll
            for (int jq = 0; jq < 16; ++jq) {
                const float4 xv = *(const float4*)(&xs[w][n * 64 + jq * 4]);  // broadcast
                a0[n] = fmaf(xv.x, w0[jq * 4 + 0], a0[n]);
                a1[n] = fmaf(xv.x, w1[jq * 4 + 0], a1[n]);
                a0[n] = fmaf(xv.y, w0[jq * 4 + 1], a0[n]);
                a1[n] = fmaf(xv.y, w1[jq * 4 + 1], a1[n]);
                a0[n] = fmaf(xv.z, w0[jq * 4 + 2], a0[n]);
                a1[n] = fmaf(xv.z, w1[jq * 4 + 2], a1[n]);
                a0[n] = fmaf(xv.w, w0[jq * 4 + 3], a0[n]);
                a1[n] = fmaf(xv.w, w1[jq * 4 + 3], a1[n]);
            }
        }
#pragma unroll
        for (int n = 0; n < 4; ++n) {
            O0[(size_t)(quad * 4 + n) * ldo0 + lane] = a0[n];
            O1[(size_t)(quad * 4 + n) * ldo1 + lane] = a1[n];
        }
    }
}

// ---------------- per-dst-node online-softmax aggregation ----------------
// One wave per dst node; 4 edges/iter; g = lane>>4 (edge slot), t = lane&15.
// PER-GROUP softmax state (m,l,acc,a5) -> zero cross-group shfls in the loop;
// flash-style 4-way state merge at the end. 2 exps/iter.
// e5 rows prefetched 2 iters ahead so the kv gather src is always resident.
__global__ __launch_bounds__(256) void k_agg(
    const float* __restrict__ q, const float* __restrict__ kv,
    const float* __restrict__ sk, const float* __restrict__ e5s,
    const float* __restrict__ wE, const int* __restrict__ row_start,
    float* __restrict__ hout) {
    const int lane = threadIdx.x & 63;
    const int g = lane >> 4, t = lane & 15;
    const int node = __builtin_amdgcn_readfirstlane(blockIdx.x * 4 + (threadIdx.x >> 6));
    if (node >= NN) return;
    const int beg = row_start[node], end = row_start[node + 1];
    if (beg == end) {
        if (g == 0)
            *(float4*)(hout + (size_t)node * 64 + t * 4) =
                *(const float4*)(sk + (size_t)node * 64 + t * 4);
        return;
    }
    const float4 q4 = *(const float4*)(q + (size_t)node * 64 + t * 4);
    // g5[c] = dot64(q, wE row c) via in-group butterfly (identical in all groups)
    float g5[5];
#pragma unroll
    for (int c = 0; c < 5; ++c) {
        const float4 w4 = *(const float4*)(wE + c * 64 + t * 4);
        float d = q4.x * w4.x;
        d = fmaf(q4.y, w4.y, d);
        d = fmaf(q4.z, w4.z, d);
        d = fmaf(q4.w, w4.w, d);
        d += __shfl_xor(d, 1);
        d += __shfl_xor(d, 2);
        d += __shfl_xor(d, 4);
        d += __shfl_xor(d, 8);
        g5[c] = d;
    }
    // per-group online-softmax state
    float m = -1e30f, l = 0.f;
    float4 accv = {0.f, 0.f, 0.f, 0.f};
    float a50 = 0.f, a51 = 0.f, a52 = 0.f, a53 = 0.f, a54 = 0.f;
    // pipeline preamble: e5 2-deep, kv 1-deep
    const int pp0 = (beg + g < end) ? beg + g : beg;
    float4 e0lo = *(const float4*)(e5s + (size_t)pp0 * 8);
    float4 e0hi = *(const float4*)(e5s + (size_t)pp0 * 8 + 4);
    const int p1x = beg + 4 + g;
    const int pp1 = (p1x < end) ? p1x : beg;
    float4 e1lo = *(const float4*)(e5s + (size_t)pp1 * 8);
    float4 e1hi = *(const float4*)(e5s + (size_t)pp1 * 8 + 4);
    const float* kp0 = kv + (size_t)__float_as_int(e0hi.y) * 128 + t * 4;
    float4 k4 = *(const float4*)(kp0);
    float4 v4 = *(const float4*)(kp0 + 64);
    for (int p = beg; p < end; p += 4) {
        // e5 prefetch for iter p+8 (sequential, L2-friendly)
        const int nx = p + 8 + g;
        const int npp = (nx < end) ? nx : beg;
        const float4 nlo = *(const float4*)(e5s + (size_t)npp * 8);
        const float4 nhi = *(const float4*)(e5s + (size_t)npp * 8 + 4);
        // kv gather for iter p+4 (e1 landed one iter ago -> no stall on src)
        const float* kpn = kv + (size_t)__float_as_int(e1hi.y) * 128 + t * 4;
        const float4 nk4 = *(const float4*)(kpn);
        const float4 nv4 = *(const float4*)(kpn + 64);
        // compute current edge (k4/v4 gathered last iter)
        const bool act = (p + g) < end;
        float d = q4.x * k4.x;
        d = fmaf(q4.y, k4.y, d);
        d = fmaf(q4.z, k4.z, d);
        d = fmaf(q4.w, k4.w, d);
        d += __shfl_xor(d, 1);
        d += __shfl_xor(d, 2);
        d += __shfl_xor(d, 4);
        d += __shfl_xor(d, 8);
        float d5 = g5[0] * e0lo.x;
        d5 = fmaf(g5[1], e0lo.y, d5);
        d5 = fmaf(g5[2], e0lo.z, d5);
        d5 = fmaf(g5[3], e0lo.w, d5);
        d5 = fmaf(g5[4], e0hi.x, d5);
        const float la = act ? (d + d5) * 0.125f : -1e30f;
        const float nm = fmaxf(m, la);
        const float scl = __expf(m - nm);
        const float pa = __expf(la - nm);
        l = fmaf(l, scl, pa);
        accv.x = fmaf(accv.x, scl, pa * v4.x);
        accv.y = fmaf(accv.y, scl, pa * v4.y);
        accv.z = fmaf(accv.z, scl, pa * v4.z);
        accv.w = fmaf(accv.w, scl, pa * v4.w);
        a50 = fmaf(a50, scl, pa * e0lo.x);
        a51 = fmaf(a51, scl, pa * e0lo.y);
        a52 = fmaf(a52, scl, pa * e0lo.z);
        a53 = fmaf(a53, scl, pa * e0lo.w);
        a54 = fmaf(a54, scl, pa * e0hi.x);
        m = nm;
        // rotate pipeline
        e0lo = e1lo;
        e0hi = e1hi;
        e1lo = nlo;
        e1hi = nhi;
        k4 = nk4;
        v4 = nv4;
    }
    // ---- merge the 4 per-group states (flash-style) ----
    float M = fmaxf(m, __shfl_xor(m, 16));
    M = fmaxf(M, __shfl_xor(M, 32));
    const float f = __expf(m - M);  // 0 for never-active groups (m=-1e30)
    float lz = l * f;
    lz += __shfl_xor(lz, 16);
    lz += __shfl_xor(lz, 32);
    accv.x *= f;
    accv.y *= f;
    accv.z *= f;
    accv.w *= f;
    a50 *= f;
    a51 *= f;
    a52 *= f;
    a53 *= f;
    a54 *= f;
#pragma unroll
    for (int s = 16; s <= 32; s <<= 1) {
        accv.x += __shfl_xor(accv.x, s);
        accv.y += __shfl_xor(accv.y, s);
        accv.z += __shfl_xor(accv.z, s);
        accv.w += __shfl_xor(accv.w, s);
        a50 += __shfl_xor(a50, s);
        a51 += __shfl_xor(a51, s);
        a52 += __shfl_xor(a52, s);
        a53 += __shfl_xor(a53, s);
        a54 += __shfl_xor(a54, s);
    }
    // fold edge-feature accumulator back through wE; add skip
    float4 t4 = accv;
    {
        const float4 w0 = *(const float4*)(wE + 0 * 64 + t * 4);
        const float4 w1 = *(const float4*)(wE + 1 * 64 + t * 4);
        const float4 w2 = *(const float4*)(wE + 2 * 64 + t * 4);
        const float4 w3 = *(const float4*)(wE + 3 * 64 + t * 4);
        const float4 w4r = *(const float4*)(wE + 4 * 64 + t * 4);
        t4.x = fmaf(a50, w0.x, t4.x);
        t4.y = fmaf(a50, w0.y, t4.y);
        t4.z = fmaf(a50, w0.z, t4.z);
        t4.w = fmaf(a50, w0.w, t4.w);
        t4.x = fmaf(a51, w1.x, t4.x);
        t4.y = fmaf(a51, w1.y, t4.y);
        t4.z = fmaf(a51, w1.z, t4.z);
        t4.w = fmaf(a51, w1.w, t4.w);
        t4.x = fmaf(a52, w2.x, t4.x);
        t4.y = fmaf(a52, w2.y, t4.y);
        t4.z = fmaf(a52, w2.z, t4.z);
        t4.w = fmaf(a52, w2.w, t4.w);
        t4.x = fmaf(a53, w3.x, t4.x);
        t4.y = fmaf(a53, w3.y, t4.y);
        t4.z = fmaf(a53, w3.z, t4.z);
        t4.w = fmaf(a53, w3.w, t4.w);
        t4.x = fmaf(a54, w4r.x, t4.x);
        t4.y = fmaf(a54, w4r.y, t4.y);
        t4.z = fmaf(a54, w4r.z, t4.z);
        t4.w = fmaf(a54, w4r.w, t4.w);
    }
    const float4 s4 = *(const float4*)(sk + (size_t)node * 64 + t * 4);
    const float rl = 1.f / lz;
    float4 o;
    o.x = fmaf(t4.x, rl, s4.x);
    o.y = fmaf(t4.y, rl, s4.y);
    o.z = fmaf(t4.z, rl, s4.z);
    o.w = fmaf(t4.w, rl, s4.w);
    if (g == 0) *(float4*)(hout + (size_t)node * 64 + t * 4) = o;
}

// ---------------- final linear HID -> 1 ----------------
__global__ __launch_bounds__(256) void k_final(const float* __restrict__ h,
                                               const float* __restrict__ lw,
                                               const float* __restrict__ lb,
                                               float* __restrict__ out) {
    const int lane = threadIdx.x & 63;
    int node = blockIdx.x * 4 + (threadIdx.x >> 6);
    if (node >= NN) return;
    float t = h[(size_t)node * 64 + lane] * lw[lane];
#pragma unroll
    for (int off = 32; off > 0; off >>= 1) t += __shfl_xor(t, off, 64);
    if (lane == 0) out[node] = t + lb[0];
}

extern "C" void kernel_launch(void* const* d_in, const int* in_sizes, int n_in,
                              void* d_out, int out_size, void* d_ws, size_t ws_size,
                              hipStream_t stream) {
    const float* x = (const float*)d_in[0];
    const int* ei = (const int*)d_in[1];
    const float* ea = (const float*)d_in[2];
    const float* w1q = (const float*)d_in[3];
    const float* b1q = (const float*)d_in[4];
    const float* w1k = (const float*)d_in[5];
    const float* b1k = (const float*)d_in[6];
    const float* w1v = (const float*)d_in[7];
    const float* b1v = (const float*)d_in[8];
    const float* w1e = (const float*)d_in[9];
    const float* w1s = (const float*)d_in[10];
    const float* b1s = (const float*)d_in[11];
    const float* wq = (const float*)d_in[12];
    const float* bq = (const float*)d_in[13];
    const float* wk = (const float*)d_in[14];
    const float* bk = (const float*)d_in[15];
    const float* wv = (const float*)d_in[16];
    const float* bv = (const float*)d_in[17];
    const float* we = (const float*)d_in[18];
    const float* ws = (const float*)d_in[19];
    const float* bs = (const float*)d_in[20];
    const float* lw = (const float*)d_in[21];
    const float* lb = (const float*)d_in[22];

    // ---- workspace carve (256B aligned), ~92 MB ----
    uintptr_t p = (uintptr_t)d_ws;
    auto alloc = [&](size_t bytes) -> void* {
        void* r = (void*)p;
        p += (bytes + 255) & ~(size_t)255;
        return r;
    };
    float* e5s = (float*)alloc((size_t)NE * 8 * 4);    // 25.6 MB, dst-sorted rows (incl. src)
    float* h0 = (float*)alloc((size_t)NN * 10 * 4);    // 2 MB
    float* hb = (float*)alloc((size_t)NN * HD * 4);    // 12.8 MB
    float* kvb = (float*)alloc((size_t)NN * 128 * 4);  // 25.6 MB interleaved k|v
    float* qb = (float*)alloc((size_t)NN * HD * 4);
    float* sb = (float*)alloc((size_t)NN * HD * 4);
    int* row_start = (int*)alloc((size_t)(NN + 1) * 4);
    int* cnt = (int*)alloc((size_t)NN * 4);
    int* cur = (int*)alloc((size_t)NN * 4);
    int* bsum = (int*)alloc((size_t)SB * 4);
    int* boff = (int*)alloc((size_t)SB * 4);

    // ---- preprocess (once per call) ----
    hipMemsetAsync(cnt, 0, (size_t)NN * 4, stream);
    k_log1p<<<(NN * 10 + 255) / 256, 256, 0, stream>>>(x, h0, NN * 10);
    k_hist<<<(NE + 255) / 256, 256, 0, stream>>>(ei, cnt);
    k_scan1<<<SB, 256, 0, stream>>>(cnt, row_start, bsum);
    k_scan2<<<1, 64, 0, stream>>>(bsum, boff, row_start);
    k_scan3<<<SB, 256, 0, stream>>>(row_start, boff, cur);
    k_scatter<<<(NE + 255) / 256, 256, 0, stream>>>(ei, ea, cur, e5s);

    const int gg = 512;                 // gemm grid (2048 waves)
    const int agg_grid = (NN + 3) / 4;  // 12500

    // ---- layer 1 (DIN=10) ----
    k_pg<10, 4><<<gg, 256, 0, stream>>>(h0, w1k, b1k, w1v, b1v, kvb, 128, kvb + 64, 128);
    k_pg<10, 4><<<gg, 256, 0, stream>>>(h0, w1q, b1q, w1s, b1s, qb, 64, sb, 64);
    k_agg<<<agg_grid, 256, 0, stream>>>(qb, kvb, sb, e5s, w1e, row_start, hb);

    // ---- layers 2..6 (DIN=64) ----
    for (int i = 0; i < 5; ++i) {
        k_pg64<<<gg, 256, 0, stream>>>(hb, wk + i * 4096, bk + i * 64,
                                       wv + i * 4096, bv + i * 64, kvb, 128, kvb + 64, 128);
        k_pg64<<<gg, 256, 0, stream>>>(hb, wq + i * 4096, bq + i * 64,
                                       ws + i * 4096, bs + i * 64, qb, 64, sb, 64);
        k_agg<<<agg_grid, 256, 0, stream>>>(qb, kvb, sb, e5s, we + i * 320, row_start, hb);
    }

    // ---- final linear ----
    k_final<<<agg_grid, 256, 0, stream>>>(hb, lw, lb, (float*)d_out);
}